// Round 4
// baseline (1045.524 us; speedup 1.0000x reference)
//
#include <hip/hip_runtime.h>

// fp16 vector types for MFMA fragments
typedef _Float16 hf2 __attribute__((ext_vector_type(2)));
typedef _Float16 hf4 __attribute__((ext_vector_type(4)));
typedef _Float16 hf8 __attribute__((ext_vector_type(8)));
typedef float    fx4 __attribute__((ext_vector_type(4)));

// async global->LDS, 16B per lane; LDS dest must be lane-linear (base + lane*16)
#define GLD16(gp, lp) __builtin_amdgcn_global_load_lds(                      \
    (const __attribute__((address_space(1))) void*)(gp),                     \
    (__attribute__((address_space(3))) void*)(lp), 16, 0, 0)

// ---------------- f32 -> f16 conversion ----------------
__global__ __launch_bounds__(256) void cvt_x_k(const float* __restrict__ s,
                                               _Float16* __restrict__ d) {
  size_t i = (size_t)blockIdx.x * 256 + threadIdx.x;  // grid 4096 -> 1,048,576 float4s
  float4 v = ((const float4*)s)[i];
  hf4 o = {(_Float16)v.x, (_Float16)v.y, (_Float16)v.z, (_Float16)v.w};
  *(hf4*)(d + 4 * i) = o;
}

__global__ __launch_bounds__(256) void cvt_w_k(const float* __restrict__ s0,
                                               const float* __restrict__ s1,
                                               const float* __restrict__ s2,
                                               const float* __restrict__ s3,
                                               _Float16* __restrict__ d) {
  const float* s = blockIdx.y == 0 ? s0 : blockIdx.y == 1 ? s1 : blockIdx.y == 2 ? s2 : s3;
  size_t i = (size_t)blockIdx.x * 256 + threadIdx.x;  // grid.x 1024 -> 262,144 float4s
  float4 v = ((const float4*)s)[i];
  hf4 o = {(_Float16)v.x, (_Float16)v.y, (_Float16)v.z, (_Float16)v.w};
  *(hf4*)(d + (size_t)blockIdx.y * 1048576 + 4 * i) = o;
}

// ---------------- 128x128 tile GEMM, C = A[M,1024] * B[N,1024]^T + bias ----------------
// mode 0: C f16, bias over n (Q,K).  mode 1: C f16, bias over m (Vt, operands swapped
// by caller so output comes out transposed).  mode 2: C f32, bias over n (out-proj).
// LDS chunk swizzle: 16B chunk ch of row r stored at physical chunk ch ^ ((r>>1)&3)
// (applied by pre-swizzling the global source; LDS dest stays lane-linear).
__device__ __forceinline__ void gemm_tile(
    const _Float16* __restrict__ A, const _Float16* __restrict__ B,
    const float* __restrict__ bias, _Float16* __restrict__ Ch,
    float* __restrict__ Cf, int m0, int n0, int ldc, int mode)
{
  __shared__ alignas(16) _Float16 Asm[2][128 * 32];
  __shared__ alignas(16) _Float16 Bsm[2][128 * 32];
  const int tid = (int)threadIdx.x;
  const int lane = tid & 63, wv = tid >> 6;
  const int col = lane & 15, g = lane >> 4;

  fx4 acc[2][8];
#pragma unroll
  for (int i = 0; i < 2; ++i)
#pragma unroll
    for (int j = 0; j < 8; ++j) acc[i][j] = fx4{0.f, 0.f, 0.f, 0.f};

  const int cp0 = tid, cp1 = tid + 256;
  const int row0 = cp0 >> 2, row1 = cp1 >> 2;
  const int ch0 = (cp0 & 3) ^ ((row0 >> 1) & 3);
  const int ch1 = (cp1 & 3) ^ ((row1 >> 1) & 3);
  const _Float16* a0 = A + (size_t)(m0 + row0) * 1024 + ch0 * 8;
  const _Float16* a1 = A + (size_t)(m0 + row1) * 1024 + ch1 * 8;
  const _Float16* b0 = B + (size_t)(n0 + row0) * 1024 + ch0 * 8;
  const _Float16* b1 = B + (size_t)(n0 + row1) * 1024 + ch1 * 8;

  int aoff[2], boff[8];
#pragma unroll
  for (int mi = 0; mi < 2; ++mi) {
    int row = wv * 32 + mi * 16 + col;
    aoff[mi] = (row * 4 + (g ^ ((row >> 1) & 3))) * 8;
  }
#pragma unroll
  for (int nj = 0; nj < 8; ++nj) {
    int row = nj * 16 + col;
    boff[nj] = (row * 4 + (g ^ ((row >> 1) & 3))) * 8;
  }

#define STAGE_T(bufi, kt) {                          \
    GLD16(a0 + (kt) * 32, &Asm[bufi][cp0 * 8]);      \
    GLD16(a1 + (kt) * 32, &Asm[bufi][cp1 * 8]);      \
    GLD16(b0 + (kt) * 32, &Bsm[bufi][cp0 * 8]);      \
    GLD16(b1 + (kt) * 32, &Bsm[bufi][cp1 * 8]); }

  STAGE_T(0, 0);
  int buf = 0;
  for (int kt = 0; kt < 32; ++kt) {
    __syncthreads();
    if (kt + 1 < 32) STAGE_T(buf ^ 1, kt + 1);
    hf8 af[2], bf[8];
#pragma unroll
    for (int mi = 0; mi < 2; ++mi) af[mi] = *(const hf8*)&Asm[buf][aoff[mi]];
#pragma unroll
    for (int nj = 0; nj < 8; ++nj) bf[nj] = *(const hf8*)&Bsm[buf][boff[nj]];
#pragma unroll
    for (int mi = 0; mi < 2; ++mi)
#pragma unroll
      for (int nj = 0; nj < 8; ++nj)
        acc[mi][nj] = __builtin_amdgcn_mfma_f32_16x16x32_f16(af[mi], bf[nj], acc[mi][nj], 0, 0, 0);
    buf ^= 1;
  }
#undef STAGE_T

  if (mode == 2) {
#pragma unroll
    for (int nj = 0; nj < 8; ++nj) {
      float bn = bias[n0 + nj * 16 + col];
#pragma unroll
      for (int mi = 0; mi < 2; ++mi)
#pragma unroll
        for (int r = 0; r < 4; ++r)
          Cf[(size_t)(m0 + wv * 32 + mi * 16 + 4 * g + r) * ldc + n0 + nj * 16 + col] =
              acc[mi][nj][r] + bn;
    }
  } else if (mode == 0) {
#pragma unroll
    for (int nj = 0; nj < 8; ++nj) {
      float bn = bias[n0 + nj * 16 + col];
#pragma unroll
      for (int mi = 0; mi < 2; ++mi)
#pragma unroll
        for (int r = 0; r < 4; ++r)
          Ch[(size_t)(m0 + wv * 32 + mi * 16 + 4 * g + r) * ldc + n0 + nj * 16 + col] =
              (_Float16)(acc[mi][nj][r] + bn);
    }
  } else {  // mode 1: bias over m
#pragma unroll
    for (int mi = 0; mi < 2; ++mi)
#pragma unroll
      for (int r = 0; r < 4; ++r) {
        float bm = bias[m0 + wv * 32 + mi * 16 + 4 * g + r];
#pragma unroll
        for (int nj = 0; nj < 8; ++nj)
          Ch[(size_t)(m0 + wv * 32 + mi * 16 + 4 * g + r) * ldc + n0 + nj * 16 + col] =
              (_Float16)(acc[mi][nj][r] + bm);
      }
  }
}

// QKV: blocks 0..255 -> Q, 256..511 -> K, 512..767 -> Vt (A=Wv, B=x -> transposed out)
__global__ __launch_bounds__(256, 3) void qkv_gemm_k(
    const _Float16* __restrict__ xh, const _Float16* __restrict__ Wqh,
    const _Float16* __restrict__ Wkh, const _Float16* __restrict__ Wvh,
    const float* __restrict__ bq, const float* __restrict__ bk,
    const float* __restrict__ bv, _Float16* __restrict__ Qh,
    _Float16* __restrict__ Kh, _Float16* __restrict__ Vt)
{
  int id = (int)blockIdx.x;
  if (id < 512) {
    int t = id & 255;
    const _Float16* Bp = (id < 256) ? Wqh : Wkh;
    const float*    bp = (id < 256) ? bq : bk;
    _Float16*       Cp = (id < 256) ? Qh : Kh;
    gemm_tile(xh, Bp, bp, Cp, nullptr, (t >> 3) * 128, (t & 7) * 128, 1024, 0);
  } else {
    int t = id - 512;  // M=1024 (e), N=4096 (b*s)
    gemm_tile(Wvh, xh, bv, Vt, nullptr, (t >> 5) * 128, (t & 31) * 128, 4096, 1);
  }
}

__global__ __launch_bounds__(256, 3) void out_gemm_k(
    const _Float16* __restrict__ Oh, const _Float16* __restrict__ Woh,
    const float* __restrict__ bo, float* __restrict__ outp)
{
  int id = (int)blockIdx.x;
  gemm_tile(Oh, Woh, bo, nullptr, outp, (id >> 3) * 128, (id & 7) * 128, 1024, 2);
}

// ---------------- attention part 1: logits + heads-softmax + attn store ----------------
// No LDS, no barriers. WG = 4 waves; wave owns one 16q x 16k tile for ALL 16 heads.
// Swapped QK^T (mfma(K,Q)) -> lane holds, for (q=q0+col, k=kt+4g+r), all 16 head
// logits in registers -> per-lane softmax over h -> direct f32x4 stores to attn.
// Grid: (ktg=32, qt=128, b=2) = 8192 WGs; waves in a WG share the Q-tile via L1.
__global__ __launch_bounds__(256, 4) void attn_sm_k(
    const _Float16* __restrict__ Qh, const _Float16* __restrict__ Kh,
    float* __restrict__ attnp)
{
  const int tid = (int)threadIdx.x;
  const int lane = tid & 63, wv = tid >> 6;
  const int col = lane & 15, g = lane >> 4;
  const int b = (int)blockIdx.z;
  const int q0 = (int)blockIdx.y * 16;
  const int kt = ((int)blockIdx.x * 4 + wv) * 16;

  const _Float16* Qrow = Qh + (size_t)(b * 2048 + q0 + col) * 1024 + g * 8;
  const _Float16* Krow = Kh + (size_t)(b * 2048 + kt + col) * 1024 + g * 8;

  fx4 lg[16];
#pragma unroll
  for (int h = 0; h < 16; ++h) lg[h] = fx4{0.f, 0.f, 0.f, 0.f};

#pragma unroll 4
  for (int h = 0; h < 16; ++h) {
    hf8 ka0 = *(const hf8*)(Krow + h * 64);
    hf8 qa0 = *(const hf8*)(Qrow + h * 64);
    hf8 ka1 = *(const hf8*)(Krow + h * 64 + 32);
    hf8 qa1 = *(const hf8*)(Qrow + h * 64 + 32);
    lg[h] = __builtin_amdgcn_mfma_f32_16x16x32_f16(ka0, qa0, lg[h], 0, 0, 0);
    lg[h] = __builtin_amdgcn_mfma_f32_16x16x32_f16(ka1, qa1, lg[h], 0, 0, 0);
  }

  // softmax over heads, per lane; element r <-> (q=q0+col, k=kt+4g+r)
  fx4 mx = lg[0];
#pragma unroll
  for (int h = 1; h < 16; ++h)
#pragma unroll
    for (int r = 0; r < 4; ++r) mx[r] = fmaxf(mx[r], lg[h][r]);
  fx4 sm = fx4{0.f, 0.f, 0.f, 0.f};
#pragma unroll
  for (int h = 0; h < 16; ++h)
#pragma unroll
    for (int r = 0; r < 4; ++r) {
      float p = __expf((lg[h][r] - mx[r]) * 0.125f);
      lg[h][r] = p;
      sm[r] += p;
    }
#pragma unroll
  for (int r = 0; r < 4; ++r) sm[r] = 1.f / sm[r];

#pragma unroll
  for (int h = 0; h < 16; ++h) {
    fx4 av;
#pragma unroll
    for (int r = 0; r < 4; ++r) av[r] = lg[h][r] * sm[r];
    *(fx4*)(attnp + (size_t)((b * 16 + h) * 2048 + q0 + col) * 2048 + kt + 4 * g) = av;
  }
}

// ---------------- attention part 2: O = P x V (reads attn f32 back) ----------------
// No LDS, no barriers, no atomics. WG = 4 waves; wave owns 16 q-rows of one (b,h);
// full K=2048 loop per wave -> single fp16 store of O. P f32x4 loads are the exact
// A-fragment of mfma_16x16x16 after in-register f16 convert; V B-frags from Vt.
// Grid: 1024 WGs (b 2 x h 16 x mt 32).
__global__ __launch_bounds__(256, 4) void pv_k(
    const float* __restrict__ attnp, const _Float16* __restrict__ Vt,
    _Float16* __restrict__ Oh)
{
  const int tid = (int)threadIdx.x;
  const int lane = tid & 63, wv = tid >> 6;
  const int col = lane & 15, g = lane >> 4;
  const int id = (int)blockIdx.x;
  const int b = id >> 9, h = (id >> 5) & 15, mt = id & 31;
  const int q0 = mt * 64 + wv * 16;

  const float* Prow = attnp + (size_t)((b * 16 + h) * 2048 + q0 + col) * 2048 + 4 * g;
  const _Float16* Vcol = Vt + (size_t)(h * 64 + col) * 4096 + b * 2048 + 4 * g;

  fx4 acc[4];
#pragma unroll
  for (int dt = 0; dt < 4; ++dt) acc[dt] = fx4{0.f, 0.f, 0.f, 0.f};

#pragma unroll 2
  for (int k0 = 0; k0 < 2048; k0 += 16) {
    float4 pv = *(const float4*)(Prow + k0);
    hf4 pa = {(_Float16)pv.x, (_Float16)pv.y, (_Float16)pv.z, (_Float16)pv.w};
#pragma unroll
    for (int dt = 0; dt < 4; ++dt) {
      hf4 vb = *(const hf4*)(Vcol + (size_t)dt * 16 * 4096 + k0);
      acc[dt] = __builtin_amdgcn_mfma_f32_16x16x16f16(pa, vb, acc[dt], 0, 0, 0);
    }
  }

  // lane holds O[q0+4g+r][h*64 + dt*16 + col]
#pragma unroll
  for (int dt = 0; dt < 4; ++dt)
#pragma unroll
    for (int r = 0; r < 4; ++r)
      Oh[(size_t)(b * 2048 + q0 + 4 * g + r) * 1024 + h * 64 + dt * 16 + col] =
          (_Float16)acc[dt][r];
}

// ---------------- launcher ----------------
extern "C" void kernel_launch(void* const* d_in, const int* in_sizes, int n_in,
                              void* d_out, int out_size, void* d_ws, size_t ws_size,
                              hipStream_t stream) {
  (void)in_sizes; (void)n_in; (void)out_size; (void)ws_size;
  const float* x  = (const float*)d_in[0];
  const float* Wq = (const float*)d_in[1];
  const float* bq = (const float*)d_in[2];
  const float* Wk = (const float*)d_in[3];
  const float* bk = (const float*)d_in[4];
  const float* Wv = (const float*)d_in[5];
  const float* bv = (const float*)d_in[6];
  const float* Wo = (const float*)d_in[7];
  const float* bo = (const float*)d_in[8];

  char* ws = (char*)d_ws;                          // layout (MB offsets):
  _Float16* xh  = (_Float16*)(ws + (0ull  << 20)); // 0..8    x fp16 [4096][1024]
  _Float16* Wqh = (_Float16*)(ws + (8ull  << 20)); // 8..10
  _Float16* Wkh = (_Float16*)(ws + (10ull << 20)); // 10..12
  _Float16* Wvh = (_Float16*)(ws + (12ull << 20)); // 12..14
  _Float16* Woh = (_Float16*)(ws + (14ull << 20)); // 14..16
  _Float16* Qh  = (_Float16*)(ws + (16ull << 20)); // 16..24  Q fp16 [4096][1024]
  _Float16* Kh  = (_Float16*)(ws + (24ull << 20)); // 24..32  K fp16
  _Float16* Vt  = (_Float16*)(ws + (32ull << 20)); // 32..40  V^T fp16 [1024][4096]
  _Float16* Oh  = (_Float16*)(ws + (40ull << 20)); // 40..48  attn-out fp16 [4096][1024]

  float* outp  = (float*)d_out;
  float* attnp = outp + 4194304ull;  // attn region [2][16][2048][2048] f32

  cvt_x_k<<<4096, 256, 0, stream>>>(x, xh);
  cvt_w_k<<<dim3(1024, 4), 256, 0, stream>>>(Wq, Wk, Wv, Wo, Wqh);
  qkv_gemm_k<<<768, 256, 0, stream>>>(xh, Wqh, Wkh, Wvh, bq, bk, bv, Qh, Kh, Vt);
  attn_sm_k<<<dim3(32, 128, 2), 256, 0, stream>>>(Qh, Kh, attnp);
  pv_k<<<1024, 256, 0, stream>>>(attnp, Vt, Oh);
  out_gemm_k<<<256, 256, 0, stream>>>(Oh, Woh, bo, outp);
}

// Round 5
// 1023.325 us; speedup vs baseline: 1.0217x; 1.0217x over previous
//
#include <hip/hip_runtime.h>

// fp16 vector types for MFMA fragments
typedef _Float16 hf2 __attribute__((ext_vector_type(2)));
typedef _Float16 hf4 __attribute__((ext_vector_type(4)));
typedef _Float16 hf8 __attribute__((ext_vector_type(8)));
typedef float    fx4 __attribute__((ext_vector_type(4)));

// async global->LDS, 16B per lane; LDS dest must be lane-linear (base + lane*16)
#define GLD16(gp, lp) __builtin_amdgcn_global_load_lds(                      \
    (const __attribute__((address_space(1))) void*)(gp),                     \
    (__attribute__((address_space(3))) void*)(lp), 16, 0, 0)

// ---------------- f32 -> f16 conversion ----------------
__global__ __launch_bounds__(256) void cvt_x_k(const float* __restrict__ s,
                                               _Float16* __restrict__ d) {
  size_t i = (size_t)blockIdx.x * 256 + threadIdx.x;  // grid 4096 -> 1,048,576 float4s
  float4 v = ((const float4*)s)[i];
  hf4 o = {(_Float16)v.x, (_Float16)v.y, (_Float16)v.z, (_Float16)v.w};
  *(hf4*)(d + 4 * i) = o;
}

__global__ __launch_bounds__(256) void cvt_w_k(const float* __restrict__ s0,
                                               const float* __restrict__ s1,
                                               const float* __restrict__ s2,
                                               const float* __restrict__ s3,
                                               _Float16* __restrict__ d) {
  const float* s = blockIdx.y == 0 ? s0 : blockIdx.y == 1 ? s1 : blockIdx.y == 2 ? s2 : s3;
  size_t i = (size_t)blockIdx.x * 256 + threadIdx.x;  // grid.x 1024 -> 262,144 float4s
  float4 v = ((const float4*)s)[i];
  hf4 o = {(_Float16)v.x, (_Float16)v.y, (_Float16)v.z, (_Float16)v.w};
  *(hf4*)(d + (size_t)blockIdx.y * 1048576 + 4 * i) = o;
}

// ---------------- 128x128 tile GEMM, C = A[M,1024] * B[N,1024]^T + bias ----------------
// mode 0: C f16, bias over n (Q,K).  mode 1: C f16, bias over m (Vt, operands swapped
// by caller so output comes out transposed).  mode 2: C f32, bias over n (out-proj).
__device__ __forceinline__ void gemm_tile(
    const _Float16* __restrict__ A, const _Float16* __restrict__ B,
    const float* __restrict__ bias, _Float16* __restrict__ Ch,
    float* __restrict__ Cf, int m0, int n0, int ldc, int mode)
{
  __shared__ alignas(16) _Float16 Asm[2][128 * 32];
  __shared__ alignas(16) _Float16 Bsm[2][128 * 32];
  const int tid = (int)threadIdx.x;
  const int lane = tid & 63, wv = tid >> 6;
  const int col = lane & 15, g = lane >> 4;

  fx4 acc[2][8];
#pragma unroll
  for (int i = 0; i < 2; ++i)
#pragma unroll
    for (int j = 0; j < 8; ++j) acc[i][j] = fx4{0.f, 0.f, 0.f, 0.f};

  const int cp0 = tid, cp1 = tid + 256;
  const int row0 = cp0 >> 2, row1 = cp1 >> 2;
  const int ch0 = (cp0 & 3) ^ ((row0 >> 1) & 3);
  const int ch1 = (cp1 & 3) ^ ((row1 >> 1) & 3);
  const _Float16* a0 = A + (size_t)(m0 + row0) * 1024 + ch0 * 8;
  const _Float16* a1 = A + (size_t)(m0 + row1) * 1024 + ch1 * 8;
  const _Float16* b0 = B + (size_t)(n0 + row0) * 1024 + ch0 * 8;
  const _Float16* b1 = B + (size_t)(n0 + row1) * 1024 + ch1 * 8;

  int aoff[2], boff[8];
#pragma unroll
  for (int mi = 0; mi < 2; ++mi) {
    int row = wv * 32 + mi * 16 + col;
    aoff[mi] = (row * 4 + (g ^ ((row >> 1) & 3))) * 8;
  }
#pragma unroll
  for (int nj = 0; nj < 8; ++nj) {
    int row = nj * 16 + col;
    boff[nj] = (row * 4 + (g ^ ((row >> 1) & 3))) * 8;
  }

#define STAGE_T(bufi, kt) {                          \
    GLD16(a0 + (kt) * 32, &Asm[bufi][cp0 * 8]);      \
    GLD16(a1 + (kt) * 32, &Asm[bufi][cp1 * 8]);      \
    GLD16(b0 + (kt) * 32, &Bsm[bufi][cp0 * 8]);      \
    GLD16(b1 + (kt) * 32, &Bsm[bufi][cp1 * 8]); }

  STAGE_T(0, 0);
  int buf = 0;
  for (int kt = 0; kt < 32; ++kt) {
    __syncthreads();
    if (kt + 1 < 32) STAGE_T(buf ^ 1, kt + 1);
    hf8 af[2], bf[8];
#pragma unroll
    for (int mi = 0; mi < 2; ++mi) af[mi] = *(const hf8*)&Asm[buf][aoff[mi]];
#pragma unroll
    for (int nj = 0; nj < 8; ++nj) bf[nj] = *(const hf8*)&Bsm[buf][boff[nj]];
#pragma unroll
    for (int mi = 0; mi < 2; ++mi)
#pragma unroll
      for (int nj = 0; nj < 8; ++nj)
        acc[mi][nj] = __builtin_amdgcn_mfma_f32_16x16x32_f16(af[mi], bf[nj], acc[mi][nj], 0, 0, 0);
    buf ^= 1;
  }
#undef STAGE_T

  if (mode == 2) {
#pragma unroll
    for (int nj = 0; nj < 8; ++nj) {
      float bn = bias[n0 + nj * 16 + col];
#pragma unroll
      for (int mi = 0; mi < 2; ++mi)
#pragma unroll
        for (int r = 0; r < 4; ++r)
          Cf[(size_t)(m0 + wv * 32 + mi * 16 + 4 * g + r) * ldc + n0 + nj * 16 + col] =
              acc[mi][nj][r] + bn;
    }
  } else if (mode == 0) {
#pragma unroll
    for (int nj = 0; nj < 8; ++nj) {
      float bn = bias[n0 + nj * 16 + col];
#pragma unroll
      for (int mi = 0; mi < 2; ++mi)
#pragma unroll
        for (int r = 0; r < 4; ++r)
          Ch[(size_t)(m0 + wv * 32 + mi * 16 + 4 * g + r) * ldc + n0 + nj * 16 + col] =
              (_Float16)(acc[mi][nj][r] + bn);
    }
  } else {  // mode 1: bias over m
#pragma unroll
    for (int mi = 0; mi < 2; ++mi)
#pragma unroll
      for (int r = 0; r < 4; ++r) {
        float bm = bias[m0 + wv * 32 + mi * 16 + 4 * g + r];
#pragma unroll
        for (int nj = 0; nj < 8; ++nj)
          Ch[(size_t)(m0 + wv * 32 + mi * 16 + 4 * g + r) * ldc + n0 + nj * 16 + col] =
              (_Float16)(acc[mi][nj][r] + bm);
      }
  }
}

// QKV: blocks 0..255 -> Q, 256..511 -> K, 512..767 -> Vt (A=Wv, B=x -> transposed out)
__global__ __launch_bounds__(256, 3) void qkv_gemm_k(
    const _Float16* __restrict__ xh, const _Float16* __restrict__ Wqh,
    const _Float16* __restrict__ Wkh, const _Float16* __restrict__ Wvh,
    const float* __restrict__ bq, const float* __restrict__ bk,
    const float* __restrict__ bv, _Float16* __restrict__ Qh,
    _Float16* __restrict__ Kh, _Float16* __restrict__ Vt)
{
  int id = (int)blockIdx.x;
  if (id < 512) {
    int t = id & 255;
    const _Float16* Bp = (id < 256) ? Wqh : Wkh;
    const float*    bp = (id < 256) ? bq : bk;
    _Float16*       Cp = (id < 256) ? Qh : Kh;
    gemm_tile(xh, Bp, bp, Cp, nullptr, (t >> 3) * 128, (t & 7) * 128, 1024, 0);
  } else {
    int t = id - 512;  // M=1024 (e), N=4096 (b*s)
    gemm_tile(Wvh, xh, bv, Vt, nullptr, (t >> 5) * 128, (t & 31) * 128, 4096, 1);
  }
}

__global__ __launch_bounds__(256, 3) void out_gemm_k(
    const _Float16* __restrict__ Oh, const _Float16* __restrict__ Woh,
    const float* __restrict__ bo, float* __restrict__ outp)
{
  int id = (int)blockIdx.x;
  gemm_tile(Oh, Woh, bo, nullptr, outp, (id >> 3) * 128, (id & 7) * 128, 1024, 2);
}

// ---------------- attention part 1: logits + heads-softmax + attn store ----------------
// 8 waves/WG; wave wv owns 16q x 16k tile (kt = k0 + wv*16) for ALL 16 heads.
// Swapped QK^T (mfma(K,Q)) -> lane holds all 16 head logits for (q=q0+col, k=kt+4g+r)
// -> per-lane softmax over h. Stores go through a small double-buffered LDS tile so
// each global_store_dwordx4 instruction writes 2 rows x 512B fully-contiguous runs
// (fixes the 4x HBM write amplification seen with 16-64B scattered row chunks).
// Grid: 1-D 4096, XCD-swizzled: xcd = id&7 owns (b = xcd>>2, q-quarter = xcd&3),
// inner order kx-outer/qy-inner keeps a 256KB K-tile L2-hot across 32 q-tiles.
__global__ __launch_bounds__(512, 2) void attn_sm_k(
    const _Float16* __restrict__ Qh, const _Float16* __restrict__ Kh,
    float* __restrict__ attnp)
{
  const int tid = (int)threadIdx.x;
  const int lane = tid & 63, wv = tid >> 6;
  const int col = lane & 15, g = lane >> 4;

  const int id = (int)blockIdx.x;
  const int xcd = id & 7, j = id >> 3;          // j: 0..511
  const int b = xcd >> 2, qq = xcd & 3;         // batch, q-quarter
  const int kx = j >> 5, qyl = j & 31;          // kx outer, qy inner
  const int q0 = (qq * 32 + qyl) * 16;
  const int k0 = kx * 128;
  const int kt = k0 + wv * 16;

  __shared__ alignas(16) float sst[2][16][136];  // [buf][q][k(128)+pad]

  const _Float16* Qrow = Qh + (size_t)(b * 2048 + q0 + col) * 1024 + g * 8;
  const _Float16* Krow = Kh + (size_t)(b * 2048 + kt + col) * 1024 + g * 8;

  fx4 lg[16];
#pragma unroll
  for (int h = 0; h < 16; ++h) lg[h] = fx4{0.f, 0.f, 0.f, 0.f};

#pragma unroll 4
  for (int h = 0; h < 16; ++h) {
    hf8 ka0 = *(const hf8*)(Krow + h * 64);
    hf8 qa0 = *(const hf8*)(Qrow + h * 64);
    hf8 ka1 = *(const hf8*)(Krow + h * 64 + 32);
    hf8 qa1 = *(const hf8*)(Qrow + h * 64 + 32);
    lg[h] = __builtin_amdgcn_mfma_f32_16x16x32_f16(ka0, qa0, lg[h], 0, 0, 0);
    lg[h] = __builtin_amdgcn_mfma_f32_16x16x32_f16(ka1, qa1, lg[h], 0, 0, 0);
  }

  // softmax over heads, per lane; element r <-> (q=q0+col, k=kt+4g+r)
  fx4 mx = lg[0];
#pragma unroll
  for (int h = 1; h < 16; ++h)
#pragma unroll
    for (int r = 0; r < 4; ++r) mx[r] = fmaxf(mx[r], lg[h][r]);
  fx4 sm = fx4{0.f, 0.f, 0.f, 0.f};
#pragma unroll
  for (int h = 0; h < 16; ++h)
#pragma unroll
    for (int r = 0; r < 4; ++r) {
      float p = __expf((lg[h][r] - mx[r]) * 0.125f);
      lg[h][r] = p;
      sm[r] += p;
    }
#pragma unroll
  for (int r = 0; r < 4; ++r) sm[r] = 1.f / sm[r];

  // store via LDS restage: per h, WG tile is [16 q][128 k] f32
  const int srow = 2 * wv + (lane >> 5);   // store-phase row (0..15)
  const int sks  = (lane & 31) * 4;        // store-phase k offset (0..124)
  float* attnbase = attnp + (size_t)(b * 16) * 2048 * 2048;
  for (int h = 0; h < 16; ++h) {
    const int buf = h & 1;
    fx4 av;
#pragma unroll
    for (int r = 0; r < 4; ++r) av[r] = lg[h][r] * sm[r];
    *(fx4*)&sst[buf][col][wv * 16 + 4 * g] = av;
    __syncthreads();
    float4 val = *(const float4*)&sst[buf][srow][sks];
    *(float4*)(attnbase + (size_t)(h * 2048 + q0 + srow) * 2048 + k0 + sks) = val;
  }
}

// ---------------- attention part 2: O = P x V (reads attn f32 back) ----------------
// No LDS, no barriers, no atomics. WG = 4 waves; wave owns 16 q-rows of one (b,h);
// full K=2048 loop per wave -> single fp16 store of O. P f32x4 loads are the exact
// A-fragment of mfma_16x16x16 after in-register f16 convert; V B-frags from Vt.
// Grid: 1024 WGs (b 2 x h 16 x mt 32).
__global__ __launch_bounds__(256, 4) void pv_k(
    const float* __restrict__ attnp, const _Float16* __restrict__ Vt,
    _Float16* __restrict__ Oh)
{
  const int tid = (int)threadIdx.x;
  const int lane = tid & 63, wv = tid >> 6;
  const int col = lane & 15, g = lane >> 4;
  const int id = (int)blockIdx.x;
  const int b = id >> 9, h = (id >> 5) & 15, mt = id & 31;
  const int q0 = mt * 64 + wv * 16;

  const float* Prow = attnp + (size_t)((b * 16 + h) * 2048 + q0 + col) * 2048 + 4 * g;
  const _Float16* Vcol = Vt + (size_t)(h * 64 + col) * 4096 + b * 2048 + 4 * g;

  fx4 acc[4];
#pragma unroll
  for (int dt = 0; dt < 4; ++dt) acc[dt] = fx4{0.f, 0.f, 0.f, 0.f};

#pragma unroll 2
  for (int k0 = 0; k0 < 2048; k0 += 16) {
    float4 pv = *(const float4*)(Prow + k0);
    hf4 pa = {(_Float16)pv.x, (_Float16)pv.y, (_Float16)pv.z, (_Float16)pv.w};
#pragma unroll
    for (int dt = 0; dt < 4; ++dt) {
      hf4 vb = *(const hf4*)(Vcol + (size_t)dt * 16 * 4096 + k0);
      acc[dt] = __builtin_amdgcn_mfma_f32_16x16x16f16(pa, vb, acc[dt], 0, 0, 0);
    }
  }

  // lane holds O[q0+4g+r][h*64 + dt*16 + col]
#pragma unroll
  for (int dt = 0; dt < 4; ++dt)
#pragma unroll
    for (int r = 0; r < 4; ++r)
      Oh[(size_t)(b * 2048 + q0 + 4 * g + r) * 1024 + h * 64 + dt * 16 + col] =
          (_Float16)acc[dt][r];
}

// ---------------- launcher ----------------
extern "C" void kernel_launch(void* const* d_in, const int* in_sizes, int n_in,
                              void* d_out, int out_size, void* d_ws, size_t ws_size,
                              hipStream_t stream) {
  (void)in_sizes; (void)n_in; (void)out_size; (void)ws_size;
  const float* x  = (const float*)d_in[0];
  const float* Wq = (const float*)d_in[1];
  const float* bq = (const float*)d_in[2];
  const float* Wk = (const float*)d_in[3];
  const float* bk = (const float*)d_in[4];
  const float* Wv = (const float*)d_in[5];
  const float* bv = (const float*)d_in[6];
  const float* Wo = (const float*)d_in[7];
  const float* bo = (const float*)d_in[8];

  char* ws = (char*)d_ws;                          // layout (MB offsets):
  _Float16* xh  = (_Float16*)(ws + (0ull  << 20)); // 0..8    x fp16 [4096][1024]
  _Float16* Wqh = (_Float16*)(ws + (8ull  << 20)); // 8..10
  _Float16* Wkh = (_Float16*)(ws + (10ull << 20)); // 10..12
  _Float16* Wvh = (_Float16*)(ws + (12ull << 20)); // 12..14
  _Float16* Woh = (_Float16*)(ws + (14ull << 20)); // 14..16
  _Float16* Qh  = (_Float16*)(ws + (16ull << 20)); // 16..24  Q fp16 [4096][1024]
  _Float16* Kh  = (_Float16*)(ws + (24ull << 20)); // 24..32  K fp16
  _Float16* Vt  = (_Float16*)(ws + (32ull << 20)); // 32..40  V^T fp16 [1024][4096]
  _Float16* Oh  = (_Float16*)(ws + (40ull << 20)); // 40..48  attn-out fp16 [4096][1024]

  float* outp  = (float*)d_out;
  float* attnp = outp + 4194304ull;  // attn region [2][16][2048][2048] f32

  cvt_x_k<<<4096, 256, 0, stream>>>(x, xh);
  cvt_w_k<<<dim3(1024, 4), 256, 0, stream>>>(Wq, Wk, Wv, Wo, Wqh);
  qkv_gemm_k<<<768, 256, 0, stream>>>(xh, Wqh, Wkh, Wvh, bq, bk, bv, Qh, Kh, Vt);
  attn_sm_k<<<4096, 512, 0, stream>>>(Qh, Kh, attnp);
  pv_k<<<1024, 256, 0, stream>>>(attnp, Vt, Oh);
  out_gemm_k<<<256, 256, 0, stream>>>(Oh, Woh, bo, outp);
}

// Round 6
// 409.402 us; speedup vs baseline: 2.5538x; 2.4996x over previous
//
#include <hip/hip_runtime.h>

// fp16 vector types for MFMA fragments
typedef _Float16 hf2 __attribute__((ext_vector_type(2)));
typedef _Float16 hf4 __attribute__((ext_vector_type(4)));
typedef _Float16 hf8 __attribute__((ext_vector_type(8)));
typedef float    fx4 __attribute__((ext_vector_type(4)));

// async global->LDS, 16B per lane; LDS dest must be lane-linear (base + lane*16)
#define GLD16(gp, lp) __builtin_amdgcn_global_load_lds(                      \
    (const __attribute__((address_space(1))) void*)(gp),                     \
    (__attribute__((address_space(3))) void*)(lp), 16, 0, 0)

// ---------------- f32 -> f16 conversion ----------------
__global__ __launch_bounds__(256) void cvt_x_k(const float* __restrict__ s,
                                               _Float16* __restrict__ d) {
  size_t i = (size_t)blockIdx.x * 256 + threadIdx.x;  // grid 4096 -> 1,048,576 float4s
  float4 v = ((const float4*)s)[i];
  hf4 o = {(_Float16)v.x, (_Float16)v.y, (_Float16)v.z, (_Float16)v.w};
  *(hf4*)(d + 4 * i) = o;
}

__global__ __launch_bounds__(256) void cvt_w_k(const float* __restrict__ s0,
                                               const float* __restrict__ s1,
                                               const float* __restrict__ s2,
                                               const float* __restrict__ s3,
                                               _Float16* __restrict__ d) {
  const float* s = blockIdx.y == 0 ? s0 : blockIdx.y == 1 ? s1 : blockIdx.y == 2 ? s2 : s3;
  size_t i = (size_t)blockIdx.x * 256 + threadIdx.x;  // grid.x 1024 -> 262,144 float4s
  float4 v = ((const float4*)s)[i];
  hf4 o = {(_Float16)v.x, (_Float16)v.y, (_Float16)v.z, (_Float16)v.w};
  *(hf4*)(d + (size_t)blockIdx.y * 1048576 + 4 * i) = o;
}

// ---------------- 128x128 tile GEMM, C = A[M,1024] * B[N,1024]^T + bias ----------------
// mode 0: C f16, bias over n (Q,K).  mode 1: C f16, bias over m (Vt, operands swapped
// by caller so output comes out transposed).  mode 2: C f32, bias over n (out-proj).
__device__ __forceinline__ void gemm_tile(
    const _Float16* __restrict__ A, const _Float16* __restrict__ B,
    const float* __restrict__ bias, _Float16* __restrict__ Ch,
    float* __restrict__ Cf, int m0, int n0, int ldc, int mode)
{
  __shared__ alignas(16) _Float16 Asm[2][128 * 32];
  __shared__ alignas(16) _Float16 Bsm[2][128 * 32];
  const int tid = (int)threadIdx.x;
  const int lane = tid & 63, wv = tid >> 6;
  const int col = lane & 15, g = lane >> 4;

  fx4 acc[2][8];
#pragma unroll
  for (int i = 0; i < 2; ++i)
#pragma unroll
    for (int j = 0; j < 8; ++j) acc[i][j] = fx4{0.f, 0.f, 0.f, 0.f};

  const int cp0 = tid, cp1 = tid + 256;
  const int row0 = cp0 >> 2, row1 = cp1 >> 2;
  const int ch0 = (cp0 & 3) ^ ((row0 >> 1) & 3);
  const int ch1 = (cp1 & 3) ^ ((row1 >> 1) & 3);
  const _Float16* a0 = A + (size_t)(m0 + row0) * 1024 + ch0 * 8;
  const _Float16* a1 = A + (size_t)(m0 + row1) * 1024 + ch1 * 8;
  const _Float16* b0 = B + (size_t)(n0 + row0) * 1024 + ch0 * 8;
  const _Float16* b1 = B + (size_t)(n0 + row1) * 1024 + ch1 * 8;

  int aoff[2], boff[8];
#pragma unroll
  for (int mi = 0; mi < 2; ++mi) {
    int row = wv * 32 + mi * 16 + col;
    aoff[mi] = (row * 4 + (g ^ ((row >> 1) & 3))) * 8;
  }
#pragma unroll
  for (int nj = 0; nj < 8; ++nj) {
    int row = nj * 16 + col;
    boff[nj] = (row * 4 + (g ^ ((row >> 1) & 3))) * 8;
  }

#define STAGE_T(bufi, kt) {                          \
    GLD16(a0 + (kt) * 32, &Asm[bufi][cp0 * 8]);      \
    GLD16(a1 + (kt) * 32, &Asm[bufi][cp1 * 8]);      \
    GLD16(b0 + (kt) * 32, &Bsm[bufi][cp0 * 8]);      \
    GLD16(b1 + (kt) * 32, &Bsm[bufi][cp1 * 8]); }

  STAGE_T(0, 0);
  int buf = 0;
  for (int kt = 0; kt < 32; ++kt) {
    __syncthreads();
    if (kt + 1 < 32) STAGE_T(buf ^ 1, kt + 1);
    hf8 af[2], bf[8];
#pragma unroll
    for (int mi = 0; mi < 2; ++mi) af[mi] = *(const hf8*)&Asm[buf][aoff[mi]];
#pragma unroll
    for (int nj = 0; nj < 8; ++nj) bf[nj] = *(const hf8*)&Bsm[buf][boff[nj]];
#pragma unroll
    for (int mi = 0; mi < 2; ++mi)
#pragma unroll
      for (int nj = 0; nj < 8; ++nj)
        acc[mi][nj] = __builtin_amdgcn_mfma_f32_16x16x32_f16(af[mi], bf[nj], acc[mi][nj], 0, 0, 0);
    buf ^= 1;
  }
#undef STAGE_T

  if (mode == 2) {
#pragma unroll
    for (int nj = 0; nj < 8; ++nj) {
      float bn = bias[n0 + nj * 16 + col];
#pragma unroll
      for (int mi = 0; mi < 2; ++mi)
#pragma unroll
        for (int r = 0; r < 4; ++r)
          Cf[(size_t)(m0 + wv * 32 + mi * 16 + 4 * g + r) * ldc + n0 + nj * 16 + col] =
              acc[mi][nj][r] + bn;
    }
  } else if (mode == 0) {
#pragma unroll
    for (int nj = 0; nj < 8; ++nj) {
      float bn = bias[n0 + nj * 16 + col];
#pragma unroll
      for (int mi = 0; mi < 2; ++mi)
#pragma unroll
        for (int r = 0; r < 4; ++r)
          Ch[(size_t)(m0 + wv * 32 + mi * 16 + 4 * g + r) * ldc + n0 + nj * 16 + col] =
              (_Float16)(acc[mi][nj][r] + bn);
    }
  } else {  // mode 1: bias over m
#pragma unroll
    for (int mi = 0; mi < 2; ++mi)
#pragma unroll
      for (int r = 0; r < 4; ++r) {
        float bm = bias[m0 + wv * 32 + mi * 16 + 4 * g + r];
#pragma unroll
        for (int nj = 0; nj < 8; ++nj)
          Ch[(size_t)(m0 + wv * 32 + mi * 16 + 4 * g + r) * ldc + n0 + nj * 16 + col] =
              (_Float16)(acc[mi][nj][r] + bm);
      }
  }
}

// QKV: blocks 0..255 -> Q, 256..511 -> K, 512..767 -> Vt (A=Wv, B=x -> transposed out)
__global__ __launch_bounds__(256, 3) void qkv_gemm_k(
    const _Float16* __restrict__ xh, const _Float16* __restrict__ Wqh,
    const _Float16* __restrict__ Wkh, const _Float16* __restrict__ Wvh,
    const float* __restrict__ bq, const float* __restrict__ bk,
    const float* __restrict__ bv, _Float16* __restrict__ Qh,
    _Float16* __restrict__ Kh, _Float16* __restrict__ Vt)
{
  int id = (int)blockIdx.x;
  if (id < 512) {
    int t = id & 255;
    const _Float16* Bp = (id < 256) ? Wqh : Wkh;
    const float*    bp = (id < 256) ? bq : bk;
    _Float16*       Cp = (id < 256) ? Qh : Kh;
    gemm_tile(xh, Bp, bp, Cp, nullptr, (t >> 3) * 128, (t & 7) * 128, 1024, 0);
  } else {
    int t = id - 512;  // M=1024 (e), N=4096 (b*s)
    gemm_tile(Wvh, xh, bv, Vt, nullptr, (t >> 5) * 128, (t & 31) * 128, 4096, 1);
  }
}

__global__ __launch_bounds__(256, 3) void out_gemm_k(
    const _Float16* __restrict__ Oh, const _Float16* __restrict__ Woh,
    const float* __restrict__ bo, float* __restrict__ outp)
{
  int id = (int)blockIdx.x;
  gemm_tile(Oh, Woh, bo, nullptr, outp, (id >> 3) * 128, (id & 7) * 128, 1024, 2);
}

// ---------------- attention part 1: logits + heads-softmax + attn store ----------------
// LDS-staged version: per head h, stage K-chunk [128 k][64 d] and Q-chunk [16 q][64 d]
// fp16 into LDS (coalesced GLD16, 16B-chunk XOR swizzle ch^(row&7) applied on the
// GLOBAL source; LDS dest lane-linear), double-buffered over h. Wave wv owns k-rows
// [k0+16wv, +16); swapped QK^T (mfma(K,Q)) -> lane (col,g) holds all 16 head logits
// for (q=q0+col, k=k0+16wv+4g+r) -> per-lane softmax over h. Store phase bounces
// each [16q][128k] head-tile through LDS so every global store is a 512B-contiguous
// run, and uses nontemporal stores (streaming; avoids L2 RFO fetch + pollution).
// Grid 4096, XCD-swizzled: xcd=id&7 -> (b, q-quarter); j: kx outer / qy inner keeps
// the 256KB K-tile L2-resident across 32 q-tiles.
__global__ __launch_bounds__(512, 4) void attn_sm_k(
    const _Float16* __restrict__ Qh, const _Float16* __restrict__ Kh,
    float* __restrict__ attnp)
{
  const int tid = (int)threadIdx.x;
  const int lane = tid & 63, wv = tid >> 6;
  const int col = lane & 15, g = lane >> 4;

  const int id = (int)blockIdx.x;
  const int xcd = id & 7, j = id >> 3;          // j: 0..511
  const int b = xcd >> 2, qq = xcd & 3;         // batch, q-quarter
  const int kx = j >> 5, qyl = j & 31;          // kx outer, qy inner
  const int q0 = (qq * 32 + qyl) * 16;
  const int k0 = kx * 128;

  __shared__ alignas(16) _Float16 Kt[2][128][64];   // 2 x 16KB
  __shared__ alignas(16) _Float16 Qt[2][16][64];    // 2 x 2KB
  __shared__ alignas(16) float    sst[2][16][136];  // 2 x 8.5KB store tiles

  const _Float16* Kbase = Kh + (size_t)(b * 2048 + k0) * 1024;
  const _Float16* Qbase = Qh + (size_t)(b * 2048 + q0) * 1024;

  // staging slots: K 1024 x 16B (2/thread), Q 128 x 16B (threads 0..127)
  const int kr0 = tid >> 3,         kc0 = tid & 7;
  const int kr1 = (tid + 512) >> 3, kc1 = (tid + 512) & 7;
  const int qr = tid >> 3,          qc = tid & 7;

#define STAGE_H(bufi, h) {                                                    \
    GLD16(Kbase + (size_t)kr0 * 1024 + (h) * 64 + (kc0 ^ (kr0 & 7)) * 8,      \
          &Kt[bufi][0][0] + tid * 8);                                         \
    GLD16(Kbase + (size_t)kr1 * 1024 + (h) * 64 + (kc1 ^ (kr1 & 7)) * 8,      \
          &Kt[bufi][0][0] + (tid + 512) * 8);                                 \
    if (tid < 128)                                                            \
      GLD16(Qbase + (size_t)qr * 1024 + (h) * 64 + (qc ^ (qr & 7)) * 8,       \
            &Qt[bufi][0][0] + tid * 8);                                       \
  }

  fx4 lg[16];
#pragma unroll
  for (int h = 0; h < 16; ++h) lg[h] = fx4{0.f, 0.f, 0.f, 0.f};

  STAGE_H(0, 0);
  int buf = 0;
  const int krow = wv * 16 + col;
#pragma unroll
  for (int h = 0; h < 16; ++h) {
    __syncthreads();
    if (h < 15) STAGE_H(buf ^ 1, h + 1);
    hf8 ka0 = *(const hf8*)&Kt[buf][krow][((0 + g) ^ (krow & 7)) * 8];
    hf8 ka1 = *(const hf8*)&Kt[buf][krow][((4 + g) ^ (krow & 7)) * 8];
    hf8 qa0 = *(const hf8*)&Qt[buf][col][((0 + g) ^ (col & 7)) * 8];
    hf8 qa1 = *(const hf8*)&Qt[buf][col][((4 + g) ^ (col & 7)) * 8];
    lg[h] = __builtin_amdgcn_mfma_f32_16x16x32_f16(ka0, qa0, lg[h], 0, 0, 0);
    lg[h] = __builtin_amdgcn_mfma_f32_16x16x32_f16(ka1, qa1, lg[h], 0, 0, 0);
    buf ^= 1;
  }
#undef STAGE_H

  // softmax over heads, per lane; element r <-> (q=q0+col, k=k0+16wv+4g+r)
  fx4 mx = lg[0];
#pragma unroll
  for (int h = 1; h < 16; ++h)
#pragma unroll
    for (int r = 0; r < 4; ++r) mx[r] = fmaxf(mx[r], lg[h][r]);
  fx4 sm = fx4{0.f, 0.f, 0.f, 0.f};
#pragma unroll
  for (int h = 0; h < 16; ++h)
#pragma unroll
    for (int r = 0; r < 4; ++r) {
      float p = __expf((lg[h][r] - mx[r]) * 0.125f);
      lg[h][r] = p;
      sm[r] += p;
    }
#pragma unroll
  for (int r = 0; r < 4; ++r) sm[r] = 1.f / sm[r];

  // store via LDS restage: per h, WG tile is [16 q][128 k] f32; nontemporal
  const int srow = 2 * wv + (lane >> 5);   // store-phase row (0..15)
  const int sks  = (lane & 31) * 4;        // store-phase k offset (0..124)
  float* attnbase = attnp + (size_t)(b * 16) * 2048 * 2048;
  for (int h = 0; h < 16; ++h) {
    const int sb = h & 1;
    fx4 av;
#pragma unroll
    for (int r = 0; r < 4; ++r) av[r] = lg[h][r] * sm[r];
    *(fx4*)&sst[sb][col][wv * 16 + 4 * g] = av;
    __syncthreads();
    fx4 val = *(const fx4*)&sst[sb][srow][sks];
    __builtin_nontemporal_store(
        val, (fx4*)(attnbase + (size_t)(h * 2048 + q0 + srow) * 2048 + k0 + sks));
  }
}

// ---------------- attention part 2: O = P x V (reads attn f32 back) ----------------
// LDS-staged: per k-chunk of 64, stage P [64 q][64 k] f32 (16KB) and V [64 d][64 k]
// f16 (8KB) via coalesced GLD16 with XOR-chunk swizzle on the global source;
// double-buffered. Wave wv owns q-rows [q0+16wv,+16); per chunk 4 ks-steps x 4
// d-tiles of mfma_16x16x16 (P A-frag from LDS f32 -> cvt f16; V B-frag ds_read_b64).
// Grid: 1024 WGs (b 2 x h 16 x mt 32 of 64 q-rows), 256 threads.
__global__ __launch_bounds__(256, 3) void pv_k(
    const float* __restrict__ attnp, const _Float16* __restrict__ Vt,
    _Float16* __restrict__ Oh)
{
  const int tid = (int)threadIdx.x;
  const int lane = tid & 63, wv = tid >> 6;
  const int col = lane & 15, g = lane >> 4;
  const int id = (int)blockIdx.x;
  const int b = id >> 9, h = (id >> 5) & 15, mt = id & 31;
  const int q0 = mt * 64;

  __shared__ alignas(16) float    Pt[2][64][64];   // 2 x 16KB
  __shared__ alignas(16) _Float16 Vl[2][64][64];   // 2 x 8KB

  const float* Pbase = attnp + (size_t)((b * 16 + h) * 2048 + q0) * 2048;
  const _Float16* Vbase = Vt + (size_t)(h * 64) * 4096 + b * 2048;

#define STAGE_PV(bufi, kc) {                                                  \
    _Pragma("unroll")                                                         \
    for (int i = 0; i < 4; ++i) {                                             \
      int s_ = tid + i * 256, row_ = s_ >> 4, cph_ = s_ & 15;                 \
      GLD16(Pbase + (size_t)row_ * 2048 + (kc) + (cph_ ^ (row_ & 15)) * 4,    \
            &Pt[bufi][0][0] + s_ * 4);                                        \
    }                                                                         \
    _Pragma("unroll")                                                         \
    for (int i = 0; i < 2; ++i) {                                             \
      int s_ = tid + i * 256, row_ = s_ >> 3, cph_ = s_ & 7;                  \
      GLD16(Vbase + (size_t)row_ * 4096 + (kc) + (cph_ ^ (row_ & 7)) * 8,     \
            &Vl[bufi][0][0] + s_ * 8);                                        \
    }                                                                         \
  }

  fx4 acc[4];
#pragma unroll
  for (int dt = 0; dt < 4; ++dt) acc[dt] = fx4{0.f, 0.f, 0.f, 0.f};

  STAGE_PV(0, 0);
  int buf = 0;
  const int prow = wv * 16 + col;
  for (int c = 0; c < 32; ++c) {
    __syncthreads();
    if (c < 31) STAGE_PV(buf ^ 1, (c + 1) * 64);
#pragma unroll
    for (int ks = 0; ks < 4; ++ks) {
      fx4 pv = *(const fx4*)&Pt[buf][prow][((ks * 4 + g) ^ col) * 4];
      hf4 pa = {(_Float16)pv[0], (_Float16)pv[1], (_Float16)pv[2], (_Float16)pv[3]};
#pragma unroll
      for (int dt = 0; dt < 4; ++dt) {
        const int vrow = dt * 16 + col;
        hf4 vb = *(const hf4*)
            &Vl[buf][vrow][(((ks * 2 + (g >> 1)) ^ (col & 7)) * 8) + (g & 1) * 4];
        acc[dt] = __builtin_amdgcn_mfma_f32_16x16x16f16(pa, vb, acc[dt], 0, 0, 0);
      }
    }
    buf ^= 1;
  }
#undef STAGE_PV

  // lane holds O[q0+16wv+4g+r][h*64 + dt*16 + col]
  const int qw = q0 + wv * 16;
#pragma unroll
  for (int dt = 0; dt < 4; ++dt)
#pragma unroll
    for (int r = 0; r < 4; ++r)
      Oh[(size_t)(b * 2048 + qw + 4 * g + r) * 1024 + h * 64 + dt * 16 + col] =
          (_Float16)acc[dt][r];
}

// ---------------- launcher ----------------
extern "C" void kernel_launch(void* const* d_in, const int* in_sizes, int n_in,
                              void* d_out, int out_size, void* d_ws, size_t ws_size,
                              hipStream_t stream) {
  (void)in_sizes; (void)n_in; (void)out_size; (void)ws_size;
  const float* x  = (const float*)d_in[0];
  const float* Wq = (const float*)d_in[1];
  const float* bq = (const float*)d_in[2];
  const float* Wk = (const float*)d_in[3];
  const float* bk = (const float*)d_in[4];
  const float* Wv = (const float*)d_in[5];
  const float* bv = (const float*)d_in[6];
  const float* Wo = (const float*)d_in[7];
  const float* bo = (const float*)d_in[8];

  char* ws = (char*)d_ws;                          // layout (MB offsets):
  _Float16* xh  = (_Float16*)(ws + (0ull  << 20)); // 0..8    x fp16 [4096][1024]
  _Float16* Wqh = (_Float16*)(ws + (8ull  << 20)); // 8..10
  _Float16* Wkh = (_Float16*)(ws + (10ull << 20)); // 10..12
  _Float16* Wvh = (_Float16*)(ws + (12ull << 20)); // 12..14
  _Float16* Woh = (_Float16*)(ws + (14ull << 20)); // 14..16
  _Float16* Qh  = (_Float16*)(ws + (16ull << 20)); // 16..24  Q fp16 [4096][1024]
  _Float16* Kh  = (_Float16*)(ws + (24ull << 20)); // 24..32  K fp16
  _Float16* Vt  = (_Float16*)(ws + (32ull << 20)); // 32..40  V^T fp16 [1024][4096]
  _Float16* Oh  = (_Float16*)(ws + (40ull << 20)); // 40..48  attn-out fp16 [4096][1024]

  float* outp  = (float*)d_out;
  float* attnp = outp + 4194304ull;  // attn region [2][16][2048][2048] f32

  cvt_x_k<<<4096, 256, 0, stream>>>(x, xh);
  cvt_w_k<<<dim3(1024, 4), 256, 0, stream>>>(Wq, Wk, Wv, Wo, Wqh);
  qkv_gemm_k<<<768, 256, 0, stream>>>(xh, Wqh, Wkh, Wvh, bq, bk, bv, Qh, Kh, Vt);
  attn_sm_k<<<4096, 512, 0, stream>>>(Qh, Kh, attnp);
  pv_k<<<1024, 256, 0, stream>>>(attnp, Vt, Oh);
  out_gemm_k<<<256, 256, 0, stream>>>(Oh, Woh, bo, outp);
}